// Round 5
// baseline (238.785 us; speedup 1.0000x reference)
//
#include <hip/hip_runtime.h>
#include <stdint.h>

#define M_DIM 4096
#define N_DIM 4096
#define K_DIM 4096
#define BM 128
#define BN 128
#define BKB 128   // K-bytes (= i8 elems) per tile

typedef __attribute__((ext_vector_type(4)))  int     int4v;   // 16 i8 A/B frag
typedef __attribute__((ext_vector_type(16))) int     int16v;  // 32x32 acc
typedef __attribute__((ext_vector_type(4)))  float   f32x4;
typedef __attribute__((ext_vector_type(8)))  uint8_t u8x8;

#define XSCALE (127.0f / 4.25f)
#define XDEQ   (4.25f / 127.0f)

// ---------------- fp32 -> i8 quantizers ----------------
__device__ __forceinline__ int8_t q8(float v) {
    float c = fminf(fmaxf(v * XSCALE, -127.0f), 127.0f);
    return (int8_t)(int)__builtin_rintf(c);
}
__device__ __forceinline__ int8_t s8(float v) {           // exact ternary sign
    return (int8_t)((v > 0.0f) - (v < 0.0f));
}

// One dispatch converts both x (quantize) and W (sign). 8 elems/thread.
__global__ __launch_bounds__(256) void cvt_i8_kernel(const float* __restrict__ x,
                                                     const float* __restrict__ w,
                                                     int8_t* __restrict__ xq,
                                                     int8_t* __restrict__ wq,
                                                     int n8each) {
    int idx = blockIdx.x * 256 + threadIdx.x;
    u8x8 o;
    if (idx < n8each) {
        const f32x4* s = (const f32x4*)x;
        f32x4 a = s[idx * 2], b = s[idx * 2 + 1];
        o[0] = (uint8_t)q8(a[0]); o[1] = (uint8_t)q8(a[1]);
        o[2] = (uint8_t)q8(a[2]); o[3] = (uint8_t)q8(a[3]);
        o[4] = (uint8_t)q8(b[0]); o[5] = (uint8_t)q8(b[1]);
        o[6] = (uint8_t)q8(b[2]); o[7] = (uint8_t)q8(b[3]);
        *(u8x8*)(xq + (size_t)idx * 8) = o;
    } else {
        int i = idx - n8each;
        const f32x4* s = (const f32x4*)w;
        f32x4 a = s[i * 2], b = s[i * 2 + 1];
        o[0] = (uint8_t)s8(a[0]); o[1] = (uint8_t)s8(a[1]);
        o[2] = (uint8_t)s8(a[2]); o[3] = (uint8_t)s8(a[3]);
        o[4] = (uint8_t)s8(b[0]); o[5] = (uint8_t)s8(b[1]);
        o[6] = (uint8_t)s8(b[2]); o[7] = (uint8_t)s8(b[3]);
        *(u8x8*)(wq + (size_t)i * 8) = o;
    }
}

// ---------------- async global->LDS, 16B per lane ----------------
__device__ __forceinline__ void gload_lds16(const int8_t* g, int8_t* l) {
    __builtin_amdgcn_global_load_lds(
        (__attribute__((address_space(1))) void*)(g),
        (__attribute__((address_space(3))) void*)(l),
        16, 0, 0);
}

// ---------------- i8 GEMM, 32x32x32 MFMA ----------------
// LDS layout identical to the verified conflict-free kernel:
// row r (128 B) split into 8x16B chunks, chunk c stored at slot c^(r&7).
__global__ __launch_bounds__(256, 2) void trix_gemm(
    const int8_t* __restrict__ A,        // xq i8 [4096][4096]
    const int8_t* __restrict__ B,        // wq i8 [4096][4096] (O-major, K contig)
    const int* __restrict__ gate,        // [4096][4]
    const float* __restrict__ scales,    // [4096]
    float* __restrict__ out)             // [4096][4096] fp32
{
    __shared__ __align__(16) int8_t As[BM * BKB];   // 16 KB
    __shared__ __align__(16) int8_t Bs[BN * BKB];   // 16 KB

    const int tid  = threadIdx.x;
    const int lane = tid & 63;
    const int wave = tid >> 6;       // 0..3
    const int wm   = wave >> 1;      // 0..1
    const int wn   = wave & 1;       // 0..1
    const int h    = lane >> 5;      // k-half selector (32x32 A/B frag)
    const int l32  = lane & 31;

    const int m0 = blockIdx.y * BM;
    const int n0 = blockIdx.x * BN;

    // ---- staging: 4 issues each for A and B per K-tile (1 KB per issue) ----
    const int srow   = lane >> 3;              // 0..7
    const int gchunk = (lane & 7) ^ srow;      // XOR swizzle in GLOBAL address
    const int8_t* a_src[4];
    const int8_t* b_src[4];
    int8_t* a_dst[4];
    int8_t* b_dst[4];
#pragma unroll
    for (int j = 0; j < 4; ++j) {
        int cidx = j * 4 + wave;
        a_src[j] = A + (size_t)(m0 + cidx * 8 + srow) * K_DIM + gchunk * 16;
        b_src[j] = B + (size_t)(n0 + cidx * 8 + srow) * K_DIM + gchunk * 16;
        a_dst[j] = As + cidx * 1024;   // 8 rows x 128 B; HW adds lane*16B
        b_dst[j] = Bs + cidx * 1024;
    }

    // ---- fragment read pointers ----
    // MFMA k-step s (K=32 window): lane (m=l32, half h) reads 16 i8 at
    // chunk c = s*2 + h of row; stored slot = c ^ (row&7).
    const int8_t* a_rd[2][4];
    const int8_t* b_rd[2][4];
#pragma unroll
    for (int ii = 0; ii < 2; ++ii) {
        int arow = wm * 64 + ii * 32 + l32;
        int brow = wn * 64 + ii * 32 + l32;
#pragma unroll
        for (int s = 0; s < 4; ++s) {
            int c = s * 2 + h;
            a_rd[ii][s] = As + arow * 128 + ((c ^ (arow & 7)) * 16);
            b_rd[ii][s] = Bs + brow * 128 + ((c ^ (brow & 7)) * 16);
        }
    }

    int16v acc[2][2];
#pragma unroll
    for (int i = 0; i < 2; ++i)
#pragma unroll
        for (int j = 0; j < 2; ++j)
            acc[i][j] = (int16v)(0);

    for (int kt = 0; kt < K_DIM; kt += BKB) {   // 32 tiles
#pragma unroll
        for (int j = 0; j < 4; ++j) {
            gload_lds16(a_src[j], a_dst[j]);
            gload_lds16(b_src[j], b_dst[j]);
        }
#pragma unroll
        for (int j = 0; j < 4; ++j) { a_src[j] += BKB; b_src[j] += BKB; }
        __syncthreads();

#pragma unroll
        for (int s = 0; s < 4; ++s) {
            int4v af[2], bf[2];
#pragma unroll
            for (int ii = 0; ii < 2; ++ii) af[ii] = *(const int4v*)a_rd[ii][s];
#pragma unroll
            for (int jj = 0; jj < 2; ++jj) bf[jj] = *(const int4v*)b_rd[jj][s];
#pragma unroll
            for (int ii = 0; ii < 2; ++ii)
#pragma unroll
                for (int jj = 0; jj < 2; ++jj)
                    acc[ii][jj] = __builtin_amdgcn_mfma_i32_32x32x32_i8(
                        af[ii], bf[jj], acc[ii][jj], 0, 0, 0);
        }
        __syncthreads();
    }

    // ---- epilogue: out = acc_i32 * (4.25/127) * scales[n] * gate[m][n>>10] ----
    // 32x32 C/D map: col = lane&31, row = (reg&3) + 8*(reg>>2) + 4*h
    const int gtile = n0 >> 10;   // block-uniform: 128 | 1024
    float sc[2];
#pragma unroll
    for (int jj = 0; jj < 2; ++jj)
        sc[jj] = scales[n0 + wn * 64 + jj * 32 + l32] * XDEQ;

#pragma unroll
    for (int ii = 0; ii < 2; ++ii) {
        int rbase = m0 + wm * 64 + ii * 32 + 4 * h;
#pragma unroll
        for (int reg = 0; reg < 16; ++reg) {
            int row = rbase + (reg & 3) + 8 * (reg >> 2);
            float g = (float)gate[row * 4 + gtile];
            float* orow = out + (size_t)row * N_DIM + n0 + wn * 64 + l32;
            orow[0]  = (float)acc[ii][0][reg] * sc[0] * g;
            orow[32] = (float)acc[ii][1][reg] * sc[1] * g;
        }
    }
}

extern "C" void kernel_launch(void* const* d_in, const int* in_sizes, int n_in,
                              void* d_out, int out_size, void* d_ws, size_t ws_size,
                              hipStream_t stream) {
    const float* x      = (const float*)d_in[0];   // [4096][4096]
    const int*   gate   = (const int*)d_in[1];     // [4096][4]
    const float* weight = (const float*)d_in[2];   // [4096][4096]
    const float* scales = (const float*)d_in[3];   // [4096]
    float* out = (float*)d_out;

    int8_t* xq = (int8_t*)d_ws;                           // 16 MB i8 x
    int8_t* wq = xq + (size_t)M_DIM * K_DIM;              // 16 MB i8 W

    const int n8each = M_DIM * K_DIM / 8;                 // 2M threads per array
    const int total_threads = 2 * n8each;
    cvt_i8_kernel<<<total_threads / 256, 256, 0, stream>>>(x, weight, xq, wq, n8each);

    dim3 grid(N_DIM / BN, M_DIM / BM);                    // 32 x 32 = 1024 blocks
    trix_gemm<<<grid, 256, 0, stream>>>(xq, wq, gate, scales, out);
}